// Round 7
// baseline (110.509 us; speedup 1.0000x reference)
//
#include <hip/hip_runtime.h>
#include <math.h>

// RansacRouting: B=32, I=1152, O=10, D=16, H=10, S=922
// Round 7: hoist mask build into K0 (coalesced sidx read, 256 uniform
// blocks, own-slot writes -> no global atomics). K1 = verified R4 single
// kernel with fragmented-sidx+scatter replaced by an 8-slot mask OR.
// Rationale: R1 (gather) vs R4 (scan) both 44us despite different middles
// => T dominated by the shared fragmented sidx phase. i-splits duplicate
// it (R5/R6); hoisting computes it once, coalesced.

#define B_    32
#define I_    1152
#define O_    10
#define D_    16
#define H_    10
#define S_    922
#define MASKW 36      // 1152/32
#define NT    384
#define NW    6       // waves per block (K1)
#define RPT   3       // rows per thread: 1152/384
#define HH    11      // 10 hypotheses + 1 "all rows" (tot)
#define NSLOT 8
#define SCH   116     // ceil(922/8) s per slot
#define K0NT  256
#define MWORDS (O_ * H_ * MASKW)   // 3600 words per (slot,b)

// ---- wave64 sum via DPP (VALU pipe, no LDS) -- result valid in lane 63 ----
template <int CTRL, int ROWM>
static __device__ __forceinline__ float dpp_f(float v) {
    return __int_as_float(__builtin_amdgcn_update_dpp(
        0, __float_as_int(v), CTRL, ROWM, 0xf, true));
}
static __device__ __forceinline__ float wave_sum_f32(float v) {
    v += dpp_f<0x111, 0xf>(v);   // row_shr:1
    v += dpp_f<0x112, 0xf>(v);   // row_shr:2
    v += dpp_f<0x114, 0xf>(v);   // row_shr:4
    v += dpp_f<0x118, 0xf>(v);   // row_shr:8
    v += dpp_f<0x142, 0xa>(v);   // row_bcast15 -> rows 1,3
    v += dpp_f<0x143, 0xc>(v);   // row_bcast31 -> rows 2,3
    return v;                    // lane 63 holds the total
}
template <int CTRL, int ROWM>
static __device__ __forceinline__ double dpp_d(double v) {
    long long x = __double_as_longlong(v);
    int lo = (int)(unsigned)(x & 0xffffffffLL);
    int hi = (int)(x >> 32);
    lo = __builtin_amdgcn_update_dpp(0, lo, CTRL, ROWM, 0xf, true);
    hi = __builtin_amdgcn_update_dpp(0, hi, CTRL, ROWM, 0xf, true);
    return __longlong_as_double((long long)(unsigned)lo | ((long long)hi << 32));
}
static __device__ __forceinline__ double wave_sum_f64(double v) {
    v += dpp_d<0x111, 0xf>(v);
    v += dpp_d<0x112, 0xf>(v);
    v += dpp_d<0x114, 0xf>(v);
    v += dpp_d<0x118, 0xf>(v);
    v += dpp_d<0x142, 0xa>(v);
    v += dpp_d<0x143, 0xc>(v);
    return v;
}

// ---------------- K0: coalesced mask build --------------------------------
// block = (b, slot k): reads s-chunk [116k, 116k+116) of b's sidx slab
// fully coalesced (int4), scatters bits for ALL 10 o's into LDS, writes its
// own maskG slot. blk = k*32+b keeps same-b blocks on XCD b&7 (L2-local
// with K1's task swizzle).
__global__ __launch_bounds__(K0NT, 2) void ransac_masks(
    const int*  __restrict__ sidx,     // [B,S,O,H]
    unsigned*   __restrict__ maskG)    // [8][32][10][10][36]
{
    __shared__ unsigned lm[MWORDS];    // 14400 B
    const int blk = blockIdx.x;
    const int b = blk & 31, k = blk >> 5;
    const int tid = threadIdx.x;

    for (int t = tid; t < MWORDS; t += K0NT) lm[t] = 0u;
    __syncthreads();

    const int s0  = k * SCH;
    const int cnt = min(S_ - s0, SCH);         // 116 (k<7) or 110 (k=7)
    const int n4  = cnt * 25;                  // cnt*100 ints / 4
    const int4* base = (const int4*)(sidx + (size_t)b * (S_ * O_ * H_)
                                          + (size_t)s0 * (O_ * H_));
    for (int j4 = tid; j4 < n4; j4 += K0NT) {
        int4 v = base[j4];
        int vv[4] = {v.x, v.y, v.z, v.w};
        int j = j4 * 4;                        // flat int index: s*100+o*10+h
        #pragma unroll
        for (int e = 0; e < 4; ++e) {
            int jj  = j + e;
            int rem = jj % 100;                // o*10 + h
            int o   = rem / 10;
            int h   = rem - 10 * o;
            int val = vv[e];                   // row index in [0,1152)
            atomicOr(&lm[(o * H_ + h) * MASKW + (val >> 5)], 1u << (val & 31));
        }
    }
    __syncthreads();

    unsigned* dst = maskG + (size_t)blk * MWORDS;   // blk == k*32+b
    for (int t = tid; t < MWORDS; t += K0NT) dst[t] = lm[t];
}

// ---------------- K1: main (R4 kernel, scatter replaced by mask OR) -------
__global__ __launch_bounds__(NT, 3) void ransac_main(
    const float*    __restrict__ up,      // [B,I,O,D]
    const unsigned* __restrict__ maskG,   // [8][32][10][10][36]
    float*          __restrict__ out)     // [B,O,D]
{
    __shared__ unsigned                 mask[H_][MASKW];    // 1440 B
    __shared__ __align__(16) float      hred[HH][NW][20];   // 5280 B
    __shared__ float                    Mu_s[H_][D_];       // 640
    __shared__ double                   lpart[H_][NW];      // 480
    __shared__ double                   losses[H_];         // 80
    __shared__ int                      hstar;

    // XCD-aware mapping: the 10 o-blocks of one b share an XCD
    const int blk = blockIdx.x;
    const int xcd = blk & 7, g = blk >> 3;
    const int gg  = g / O_;
    const int b   = xcd + 8 * gg;
    const int o   = g - O_ * gg;
    const int bo  = b * O_ + o;

    const int tid  = threadIdx.x;
    const int lane = tid & 63;
    const int wv   = tid >> 6;

    // (1) mask slot loads -- consumed first (L2-hot, coalesced)
    unsigned mw8[NSLOT];
    const bool mt = tid < H_ * MASKW;          // 360 threads
    if (mt) {
        #pragma unroll
        for (int k = 0; k < NSLOT; ++k)
            mw8[k] = maskG[(size_t)(k * 32 + b) * MWORDS + o * (H_ * MASKW) + tid];
    }

    // (2) u-row loads -- consumed second (vn/scan phases)
    const float* ub = up + ((size_t)b * I_ * O_ + o) * D_;
    float4 R[RPT][4];
    #pragma unroll
    for (int r = 0; r < RPT; ++r) {
        const float4* p = (const float4*)(ub + (size_t)(tid + r * NT) * (O_ * D_));
        R[r][0] = p[0]; R[r][1] = p[1]; R[r][2] = p[2]; R[r][3] = p[3];
    }

    // (3) OR the 8 slots -> LDS mask (waits only on mask loads, oldest)
    if (mt) {
        unsigned m = mw8[0];
        #pragma unroll
        for (int k = 1; k < NSLOT; ++k) m |= mw8[k];
        ((unsigned*)mask)[tid] = m;
    }

    // (4) vn + usq per register row (drains u loads)
    float vn[RPT], usq[RPT];
    #pragma unroll
    for (int r = 0; r < RPT; ++r) {
        float4 q0 = R[r][0], q1 = R[r][1], q2 = R[r][2], q3 = R[r][3];
        float s = q0.x*q0.x + q0.y*q0.y + q0.z*q0.z + q0.w*q0.w
                + q1.x*q1.x + q1.y*q1.y + q1.z*q1.z + q1.w*q1.w
                + q2.x*q2.x + q2.y*q2.y + q2.z*q2.z + q2.w*q2.w
                + q3.x*q3.x + q3.y*q3.y + q3.z*q3.z + q3.w*q3.w;
        vn[r] = sqrtf(s);
        float uq[D_] = {q0.x,q0.y,q0.z,q0.w, q1.x,q1.y,q1.z,q1.w,
                        q2.x,q2.y,q2.z,q2.w, q3.x,q3.y,q3.z,q3.w};
        float t = 0.f;
        #pragma unroll
        for (int d = 0; d < D_; ++d) t = fmaf(uq[d], uq[d], t);
        usq[r] = t;
    }
    __syncthreads();   // mask complete

    // (5) masked scan: h<10 -> complement sums; h==10 -> tot (all rows)
    const int      w0   = tid >> 5;            // base mask word for row tid
    const unsigned bitm = 1u << (tid & 31);
    for (int h = 0; h < HH; ++h) {
        float na[17];
        #pragma unroll
        for (int d = 0; d < 17; ++d) na[d] = 0.f;
        #pragma unroll
        for (int r = 0; r < RPT; ++r) {
            float w = vn[r];
            if (h < H_) {
                unsigned mw = mask[h][w0 + 12 * r];
                w = (mw & bitm) ? 0.f : w;     // sampled row -> excluded
            }
            float4 q0 = R[r][0], q1 = R[r][1], q2 = R[r][2], q3 = R[r][3];
            na[ 0] = fmaf(w, q0.x, na[ 0]); na[ 1] = fmaf(w, q0.y, na[ 1]);
            na[ 2] = fmaf(w, q0.z, na[ 2]); na[ 3] = fmaf(w, q0.w, na[ 3]);
            na[ 4] = fmaf(w, q1.x, na[ 4]); na[ 5] = fmaf(w, q1.y, na[ 5]);
            na[ 6] = fmaf(w, q1.z, na[ 6]); na[ 7] = fmaf(w, q1.w, na[ 7]);
            na[ 8] = fmaf(w, q2.x, na[ 8]); na[ 9] = fmaf(w, q2.y, na[ 9]);
            na[10] = fmaf(w, q2.z, na[10]); na[11] = fmaf(w, q2.w, na[11]);
            na[12] = fmaf(w, q3.x, na[12]); na[13] = fmaf(w, q3.y, na[13]);
            na[14] = fmaf(w, q3.z, na[14]); na[15] = fmaf(w, q3.w, na[15]);
            na[16] += w;
        }
        #pragma unroll
        for (int d = 0; d < 17; ++d) na[d] = wave_sum_f32(na[d]);
        if (lane == 63) {
            *(float4*)&hred[h][wv][ 0] = make_float4(na[ 0], na[ 1], na[ 2], na[ 3]);
            *(float4*)&hred[h][wv][ 4] = make_float4(na[ 4], na[ 5], na[ 6], na[ 7]);
            *(float4*)&hred[h][wv][ 8] = make_float4(na[ 8], na[ 9], na[10], na[11]);
            *(float4*)&hred[h][wv][12] = make_float4(na[12], na[13], na[14], na[15]);
            hred[h][wv][16] = na[16];
        }
    }
    __syncthreads();   // hred complete

    // (6) Mu finalize: Mu_h[d] = (tot[d]-na_h[d]) / (tot[16]-na_h[16])
    for (int h = wv; h < H_; h += NW) {
        if (lane < D_) {
            float naj = 0.f, totj = 0.f, na16 = 0.f, tot16 = 0.f;
            #pragma unroll
            for (int w = 0; w < NW; ++w) {
                naj   += hred[h ][w][lane];
                totj  += hred[10][w][lane];
                na16  += hred[h ][w][16];
                tot16 += hred[10][w][16];
            }
            float rd = 1.f / (tot16 - na16);
            Mu_s[h][lane] = (totj - naj) * rd;
        }
    }
    __syncthreads();   // Mu ready

    // (7) loss: h-outer over register-resident rows; Mu broadcast from LDS
    for (int h = 0; h < H_; ++h) {
        float4 m0 = *(const float4*)&Mu_s[h][0];
        float4 m1 = *(const float4*)&Mu_s[h][4];
        float4 m2 = *(const float4*)&Mu_s[h][8];
        float4 m3 = *(const float4*)&Mu_s[h][12];
        float mv[D_] = {m0.x, m0.y, m0.z, m0.w, m1.x, m1.y, m1.z, m1.w,
                        m2.x, m2.y, m2.z, m2.w, m3.x, m3.y, m3.z, m3.w};
        float musq = 0.f;
        #pragma unroll
        for (int d = 0; d < D_; ++d) musq = fmaf(mv[d], mv[d], musq);
        double l = 0.0;
        #pragma unroll
        for (int r = 0; r < RPT; ++r) {
            float uq[D_] = {R[r][0].x, R[r][0].y, R[r][0].z, R[r][0].w,
                            R[r][1].x, R[r][1].y, R[r][1].z, R[r][1].w,
                            R[r][2].x, R[r][2].y, R[r][2].z, R[r][2].w,
                            R[r][3].x, R[r][3].y, R[r][3].z, R[r][3].w};
            float dot = 0.f;
            #pragma unroll
            for (int d = 0; d < D_; ++d) dot = fmaf(uq[d], mv[d], dot);
            float d2 = fmaf(-2.f, dot, usq[r] + musq);
            l += (double)sqrtf(fmaxf(d2, 0.f));
        }
        l = wave_sum_f64(l);
        if (lane == 63) lpart[h][wv] = l;
    }
    __syncthreads();

    if (tid < H_) {
        double t = 0.0;
        #pragma unroll
        for (int w = 0; w < NW; ++w) t += lpart[tid][w];
        losses[tid] = t;
    }
    __syncthreads();
    if (tid == 0) {
        int best = 0; double bl = losses[0];
        #pragma unroll
        for (int h = 1; h < H_; ++h)
            if (losses[h] < bl) { bl = losses[h]; best = h; }
        hstar = best;
    }
    __syncthreads();
    if (tid < D_)
        out[(size_t)bo * D_ + tid] = Mu_s[hstar][tid];
}

extern "C" void kernel_launch(void* const* d_in, const int* in_sizes, int n_in,
                              void* d_out, int out_size, void* d_ws, size_t ws_size,
                              hipStream_t stream) {
    const float* up   = (const float*)d_in[0];
    const int*   sidx = (const int*)d_in[1];
    float*       out  = (float*)d_out;
    unsigned*    maskG = (unsigned*)d_ws;    // 8*32*3600*4 = 4.6 MB
    ransac_masks<<<NSLOT * B_, K0NT, 0, stream>>>(sidx, maskG);
    ransac_main<<<B_ * O_, NT, 0, stream>>>(up, maskG, out);
}